// Round 8
// baseline (538.740 us; speedup 1.0000x reference)
//
#include <hip/hip_runtime.h>

// MultiHeadAttention: B=2, S=4096, D=512, H=8, depth=64. fp32 in/out.
// mfma_f32_16x16x32_f16 everywhere, fp32 accum. S^T = K Q^T flash (one q-row
// per lane, register-shuffled P). Round 8: software-pipelined staging
// (prefetch tile t+1 into VGPRs during compute of tile t) + fused QKV
// projection launch. Q pre-scaled by log2(e); softmax in exp2 units.
#define NH   8
#define DH   64
#define NB   2
#define SEQ  4096
#define DM   512
#define MR   (NB * SEQ)
#define LSTR 72          // LDS row stride in halves (144 B, 16B-aligned)
#define LOG2E 1.44269504089f

using f16x8 = __attribute__((ext_vector_type(8))) _Float16;
using f32x4 = __attribute__((ext_vector_type(4))) float;
#define MFMA16(a, b, c) __builtin_amdgcn_mfma_f32_16x16x32_f16(a, b, c, 0, 0, 0)

__device__ __forceinline__ unsigned pk_f16(float a, float b) {
    typedef __fp16 fp16v2 __attribute__((ext_vector_type(2)));
    union { fp16v2 h; unsigned u; } c;
    c.h = __builtin_amdgcn_cvt_pkrtz(a, b);   // v_cvt_pkrtz_f16_f32
    return c.u;
}
__device__ __forceinline__ unsigned sel_shfl(unsigned a, unsigned b, int pick, int src) {
    const unsigned va = __shfl(a, src);
    const unsigned vb = __shfl(b, src);
    return pick ? vb : va;
}

// ---------------------------------------------------------------------------
// W fp32 [k][n] -> Wt f16 [n][k], 4 weights (blockIdx.z). grid (8,8,4) x 256.
// ---------------------------------------------------------------------------
__global__ __launch_bounds__(256) void cvt_w(
    const float* __restrict__ w0, const float* __restrict__ w1,
    const float* __restrict__ w2, const float* __restrict__ w3,
    _Float16* __restrict__ Wt)
{
    __shared__ _Float16 T[64 * LSTR];
    const int z = blockIdx.z;
    const float* W = (z == 0) ? w0 : (z == 1 ? w1 : (z == 2 ? w2 : w3));
    _Float16* out = Wt + (size_t)z * DM * DM;
    const int t = threadIdx.x;
    const int k0 = blockIdx.x * 64, n0 = blockIdx.y * 64;
#pragma unroll
    for (int i = 0; i < 4; ++i) {
        const int kl  = i * 16 + (t >> 4);
        const int nl4 = (t & 15) * 4;
        float4 u = *(const float4*)(W + (size_t)(k0 + kl) * DM + n0 + nl4);
        T[(nl4 + 0) * LSTR + kl] = (_Float16)u.x;
        T[(nl4 + 1) * LSTR + kl] = (_Float16)u.y;
        T[(nl4 + 2) * LSTR + kl] = (_Float16)u.z;
        T[(nl4 + 3) * LSTR + kl] = (_Float16)u.w;
    }
    __syncthreads();
#pragma unroll
    for (int i = 0; i < 2; ++i) {
        const int nl = i * 32 + (t >> 3);
        const int kc = (t & 7) * 8;
        *(uint4*)(out + (size_t)(n0 + nl) * DM + k0 + kc) = *(const uint4*)&T[nl * LSTR + kc];
    }
}

// ---------------------------------------------------------------------------
// Fused QKV projection. X = q/k/v (fp32) by blockIdx.z; Wt f16 [3][n][k].
// z<2: head-split f16 [B,H,S,64]; z==2: transposed [B,H,64,S] for V.
// Q scaled by log2e. grid (MR/128, 8, 3), block 256. Prefetch-pipelined.
// ---------------------------------------------------------------------------
__global__ __launch_bounds__(256) void proj_qkv(
    const float* __restrict__ q, const float* __restrict__ k,
    const float* __restrict__ v, const _Float16* __restrict__ Wt,
    const float* __restrict__ bqp, const float* __restrict__ bkp,
    const float* __restrict__ bvp,
    _Float16* __restrict__ Qo, _Float16* __restrict__ Ko,
    _Float16* __restrict__ VTo)
{
    __shared__ _Float16 Xs[128 * LSTR];   // [row][k]
    __shared__ _Float16 Ws[64 * LSTR];    // [n][k]

    const int z = blockIdx.z;
    const float* X = (z == 0) ? q : (z == 1 ? k : v);
    const _Float16* W = Wt + (size_t)z * DM * DM;
    const float* bias = (z == 0) ? bqp : (z == 1 ? bkp : bvp);
    const float scale = (z == 0) ? LOG2E : 1.0f;

    const int t = threadIdx.x;
    const int l = t & 63, w = t >> 6;
    const int m = l & 15, g = l >> 4;
    const int row0 = blockIdx.x * 128;
    const int col0 = blockIdx.y * 64;

    const int xr = t >> 4, xc = (t & 15) * 4;
    const int wn = t >> 3, wc = (t & 7) * 8;

    f32x4 acc[2][4] = {};

    // prefetch k0 = 0
    float4 xreg[8];
    uint4  wreg[2];
#pragma unroll
    for (int i = 0; i < 8; ++i)
        xreg[i] = *(const float4*)(X + (size_t)(row0 + i * 16 + xr) * DM + xc);
#pragma unroll
    for (int i = 0; i < 2; ++i)
        wreg[i] = *(const uint4*)(W + (size_t)(col0 + i * 32 + wn) * DM + wc);

    for (int k0 = 0; k0 < DM; k0 += 64) {
        // commit prefetched tile to LDS
#pragma unroll
        for (int i = 0; i < 8; ++i) {
            uint2 p = make_uint2(pk_f16(xreg[i].x, xreg[i].y),
                                 pk_f16(xreg[i].z, xreg[i].w));
            *(uint2*)&Xs[(i * 16 + xr) * LSTR + xc] = p;
        }
#pragma unroll
        for (int i = 0; i < 2; ++i)
            *(uint4*)&Ws[(i * 32 + wn) * LSTR + wc] = wreg[i];
        __syncthreads();

        // issue next tile's loads (overlap with MFMA below)
        const int kn = (k0 + 64) & (DM - 1);
#pragma unroll
        for (int i = 0; i < 8; ++i)
            xreg[i] = *(const float4*)(X + (size_t)(row0 + i * 16 + xr) * DM + kn + xc);
#pragma unroll
        for (int i = 0; i < 2; ++i)
            wreg[i] = *(const uint4*)(W + (size_t)(col0 + i * 32 + wn) * DM + kn + wc);

#pragma unroll
        for (int kk = 0; kk < 2; ++kk) {
            f16x8 a0 = *(const f16x8*)&Xs[(w * 32 + m) * LSTR + kk * 32 + g * 8];
            f16x8 a1 = *(const f16x8*)&Xs[(w * 32 + 16 + m) * LSTR + kk * 32 + g * 8];
#pragma unroll
            for (int ct = 0; ct < 4; ++ct) {
                f16x8 bf = *(const f16x8*)&Ws[(ct * 16 + m) * LSTR + kk * 32 + g * 8];
                acc[0][ct] = MFMA16(a0, bf, acc[0][ct]);
                acc[1][ct] = MFMA16(a1, bf, acc[1][ct]);
            }
        }
        __syncthreads();
    }

    float bv4[4];
#pragma unroll
    for (int ct = 0; ct < 4; ++ct) bv4[ct] = bias[col0 + ct * 16 + m];

    if (z == 2) {
        // V: transpose 128x64 tile in LDS (reuse Xs as T[64][136])
        _Float16* T = Xs;
#pragma unroll
        for (int rt = 0; rt < 2; ++rt)
#pragma unroll
            for (int reg = 0; reg < 4; ++reg) {
                const int s_l = w * 32 + rt * 16 + g * 4 + reg;
#pragma unroll
                for (int ct = 0; ct < 4; ++ct) {
                    const int d = ct * 16 + m;
                    T[d * 136 + s_l] = (_Float16)(acc[rt][ct][reg] + bv4[ct]);
                }
            }
        __syncthreads();
        const int bb = row0 >> 12;
        const int s0 = row0 & (SEQ - 1);
#pragma unroll
        for (int j = 0; j < 4; ++j) {
            const int c = j * 256 + t;
            const int d = c >> 4;
            const int sc = (c & 15) * 8;
            *(uint4*)(VTo + (((size_t)bb * NH + blockIdx.y) * DH + d) * SEQ + s0 + sc) =
                *(const uint4*)&T[d * 136 + sc];
        }
    } else {
        _Float16* out = (z == 0) ? Qo : Ko;
#pragma unroll
        for (int rt = 0; rt < 2; ++rt)
#pragma unroll
            for (int reg = 0; reg < 4; ++reg) {
                const int row = row0 + w * 32 + rt * 16 + g * 4 + reg;
                const int bb = row >> 12;
                const int s  = row & (SEQ - 1);
#pragma unroll
                for (int ct = 0; ct < 4; ++ct) {
                    out[(((size_t)bb * NH + blockIdx.y) * SEQ + s) * DH + ct * 16 + m] =
                        (_Float16)(scale * (acc[rt][ct][reg] + bv4[ct]));
                }
            }
    }
}

// ---------------------------------------------------------------------------
// Output GEMM: d_out[M,512] fp32 = Ows[M,512](f16) @ Wo + bo. Prefetched.
// grid (MR/128, 8), block 256.
// ---------------------------------------------------------------------------
__global__ __launch_bounds__(256) void gemm_out(const _Float16* __restrict__ X,
                                                const _Float16* __restrict__ Wt,
                                                const float* __restrict__ bias,
                                                float* __restrict__ out)
{
    __shared__ _Float16 Xs[128 * LSTR];
    __shared__ _Float16 Ws[64 * LSTR];

    const int t = threadIdx.x;
    const int l = t & 63, w = t >> 6;
    const int m = l & 15, g = l >> 4;
    const int row0 = blockIdx.x * 128;
    const int col0 = blockIdx.y * 64;

    const int xr = t >> 3, xc = (t & 7) * 8;

    f32x4 acc[2][4] = {};

    uint4 xreg[4], wreg[2];
#pragma unroll
    for (int i = 0; i < 4; ++i)
        xreg[i] = *(const uint4*)(X + (size_t)(row0 + i * 32 + xr) * DM + xc);
#pragma unroll
    for (int i = 0; i < 2; ++i)
        wreg[i] = *(const uint4*)(Wt + (size_t)(col0 + i * 32 + xr) * DM + xc);

    for (int k0 = 0; k0 < DM; k0 += 64) {
#pragma unroll
        for (int i = 0; i < 4; ++i)
            *(uint4*)&Xs[(i * 32 + xr) * LSTR + xc] = xreg[i];
#pragma unroll
        for (int i = 0; i < 2; ++i)
            *(uint4*)&Ws[(i * 32 + xr) * LSTR + xc] = wreg[i];
        __syncthreads();

        const int kn = (k0 + 64) & (DM - 1);
#pragma unroll
        for (int i = 0; i < 4; ++i)
            xreg[i] = *(const uint4*)(X + (size_t)(row0 + i * 32 + xr) * DM + kn + xc);
#pragma unroll
        for (int i = 0; i < 2; ++i)
            wreg[i] = *(const uint4*)(Wt + (size_t)(col0 + i * 32 + xr) * DM + kn + xc);

#pragma unroll
        for (int kk = 0; kk < 2; ++kk) {
            f16x8 a0 = *(const f16x8*)&Xs[(w * 32 + m) * LSTR + kk * 32 + g * 8];
            f16x8 a1 = *(const f16x8*)&Xs[(w * 32 + 16 + m) * LSTR + kk * 32 + g * 8];
#pragma unroll
            for (int ct = 0; ct < 4; ++ct) {
                f16x8 bf = *(const f16x8*)&Ws[(ct * 16 + m) * LSTR + kk * 32 + g * 8];
                acc[0][ct] = MFMA16(a0, bf, acc[0][ct]);
                acc[1][ct] = MFMA16(a1, bf, acc[1][ct]);
            }
        }
        __syncthreads();
    }

    float bv4[4];
#pragma unroll
    for (int ct = 0; ct < 4; ++ct) bv4[ct] = bias[col0 + ct * 16 + m];

#pragma unroll
    for (int rt = 0; rt < 2; ++rt)
#pragma unroll
        for (int reg = 0; reg < 4; ++reg) {
            const int row = row0 + w * 32 + rt * 16 + g * 4 + reg;
#pragma unroll
            for (int ct = 0; ct < 4; ++ct)
                out[(size_t)row * DM + col0 + ct * 16 + m] = acc[rt][ct][reg] + bv4[ct];
        }
}

// ---------------------------------------------------------------------------
// Flash attention, S^T formulation, prefetch-pipelined K/V staging.
// Q(log2e-scaled),K f16 [B*H,S,64]; VT f16 [B*H,64,S]; mask fp32 [B,1,1,S];
// O f16 [B,S,512]. grid (S/64, B*H), block 256. LDS 27 KiB.
// ---------------------------------------------------------------------------
__global__ __launch_bounds__(256) void flash_mfma(
    const _Float16* __restrict__ Q, const _Float16* __restrict__ K,
    const _Float16* __restrict__ VT, const float* __restrict__ mask,
    _Float16* __restrict__ O)
{
    __shared__ _Float16 Qs [64 * LSTR];  // [qrow][dim]
    __shared__ _Float16 Ks [64 * LSTR];  // [key][dim]
    __shared__ _Float16 VTs[64 * LSTR];  // [dim][key]

    const int t = threadIdx.x;
    const int l = t & 63, w = t >> 6;
    const int m = l & 15, g = l >> 4;
    const int bh = blockIdx.y;
    const int b  = bh >> 3;
    const int h  = bh & 7;
    const int q0 = blockIdx.x * 64;

    const _Float16* Qh  = Q  + (size_t)bh * SEQ * DH;
    const _Float16* Kh  = K  + (size_t)bh * SEQ * DH;
    const _Float16* VTh = VT + (size_t)bh * DH * SEQ;
    const float* maskb = mask + (size_t)b * SEQ;

    const int sr = t >> 3, sc = (t & 7) * 8;   // staging row/col

#pragma unroll
    for (int i = 0; i < 2; ++i)
        *(uint4*)&Qs[(i * 32 + sr) * LSTR + sc] =
            *(const uint4*)(Qh + (size_t)(q0 + i * 32 + sr) * DH + sc);

    float m_r = -INFINITY, l_r = 0.f;
    f32x4 oacc[4] = {};

    // register-shuffle sources for the P^T -> B-fragment transform
    const int srcA = m + (((g * 2) & 3) << 4);
    const int srcB = m + (((g * 2 + 1) & 3) << 4);
    const int pick = g >> 1;

    // prefetch tile 0
    uint4 kreg[2], vreg[2];
#pragma unroll
    for (int i = 0; i < 2; ++i) {
        kreg[i] = *(const uint4*)(Kh + (size_t)(i * 32 + sr) * DH + sc);
        vreg[i] = *(const uint4*)(VTh + (size_t)(i * 32 + sr) * SEQ + sc);
    }

    for (int t0 = 0; t0 < SEQ; t0 += 64) {
        // commit prefetched K/VT to LDS
#pragma unroll
        for (int i = 0; i < 2; ++i) {
            *(uint4*)&Ks[(i * 32 + sr) * LSTR + sc]  = kreg[i];
            *(uint4*)&VTs[(i * 32 + sr) * LSTR + sc] = vreg[i];
        }
        __syncthreads();

        // issue next tile's loads (overlap with compute below)
        const int tn = (t0 + 64) & (SEQ - 1);
#pragma unroll
        for (int i = 0; i < 2; ++i) {
            kreg[i] = *(const uint4*)(Kh + (size_t)(tn + i * 32 + sr) * DH + sc);
            vreg[i] = *(const uint4*)(VTh + (size_t)(i * 32 + sr) * SEQ + tn + sc);
        }

        // ---- S^T = K Q^T : sacc[kt] rows = keys kt*16 + g*4 + reg, col q = m
        f32x4 sacc[4] = {};
#pragma unroll
        for (int kk = 0; kk < 2; ++kk) {
            f16x8 qf = *(const f16x8*)&Qs[(w * 16 + m) * LSTR + kk * 32 + g * 8];
#pragma unroll
            for (int kt = 0; kt < 4; ++kt) {
                f16x8 kf = *(const f16x8*)&Ks[(kt * 16 + m) * LSTR + kk * 32 + g * 8];
                sacc[kt] = MFMA16(kf, qf, sacc[kt]);
            }
        }

        // ---- mask (per-key, fma) ----
        const float mc = -1e9f * LOG2E;
#pragma unroll
        for (int kt = 0; kt < 4; ++kt) {
            const float4 mk = *(const float4*)&maskb[t0 + kt * 16 + g * 4];
            sacc[kt][0] = fmaf(mk.x, mc, sacc[kt][0]);
            sacc[kt][1] = fmaf(mk.y, mc, sacc[kt][1]);
            sacc[kt][2] = fmaf(mk.z, mc, sacc[kt][2]);
            sacc[kt][3] = fmaf(mk.w, mc, sacc[kt][3]);
        }

        // ---- online softmax, scalar state per lane (one q-row each) ----
        float rmax = -INFINITY;
#pragma unroll
        for (int kt = 0; kt < 4; ++kt) {
            rmax = fmaxf(rmax, fmaxf(fmaxf(sacc[kt][0], sacc[kt][1]),
                                     fmaxf(sacc[kt][2], sacc[kt][3])));
        }
        rmax = fmaxf(rmax, __shfl_xor(rmax, 16));
        rmax = fmaxf(rmax, __shfl_xor(rmax, 32));
        const float mnew  = fmaxf(m_r, rmax);
        const float alpha = exp2f(m_r - mnew);   // first tile: exp2(-inf)=0
        m_r = mnew;

        float psum = 0.f;
        unsigned pkw[4][2];
#pragma unroll
        for (int kt = 0; kt < 4; ++kt) {
            const float p0 = exp2f(sacc[kt][0] - mnew);
            const float p1 = exp2f(sacc[kt][1] - mnew);
            const float p2 = exp2f(sacc[kt][2] - mnew);
            const float p3 = exp2f(sacc[kt][3] - mnew);
            psum += (p0 + p1) + (p2 + p3);
            pkw[kt][0] = pk_f16(p0, p1);
            pkw[kt][1] = pk_f16(p2, p3);
        }
        l_r = l_r * alpha + psum;
#pragma unroll
        for (int dt = 0; dt < 4; ++dt)
#pragma unroll
            for (int r = 0; r < 4; ++r) oacc[dt][r] *= alpha;

        // ---- O^T += V^T P^T ; B-frag assembled by register shuffle ----
#pragma unroll
        for (int kk = 0; kk < 2; ++kk) {
            union { unsigned u[4]; f16x8 h; } pf;
            pf.u[0] = sel_shfl(pkw[2 * kk][0], pkw[2 * kk + 1][0], pick, srcA);
            pf.u[1] = sel_shfl(pkw[2 * kk][1], pkw[2 * kk + 1][1], pick, srcA);
            pf.u[2] = sel_shfl(pkw[2 * kk][0], pkw[2 * kk + 1][0], pick, srcB);
            pf.u[3] = sel_shfl(pkw[2 * kk][1], pkw[2 * kk + 1][1], pick, srcB);
#pragma unroll
            for (int dt = 0; dt < 4; ++dt) {
                f16x8 vf = *(const f16x8*)&VTs[(dt * 16 + m) * LSTR + kk * 32 + g * 8];
                oacc[dt] = MFMA16(vf, pf.h, oacc[dt]);
            }
        }
        __syncthreads();   // Ks/VTs consumed; next commit may overwrite
    }

    // ---- final l reduction + store (O^T: lane q = m, dims dt*16+g*4+reg) ----
    l_r += __shfl_xor(l_r, 16);
    l_r += __shfl_xor(l_r, 32);
    const float inv = 1.0f / l_r;
    const int q = q0 + w * 16 + m;
    _Float16* Orow = O + ((size_t)b * SEQ + q) * DM + h * DH;
#pragma unroll
    for (int dt = 0; dt < 4; ++dt) {
        _Float16 o4[4] = { (_Float16)(oacc[dt][0] * inv), (_Float16)(oacc[dt][1] * inv),
                           (_Float16)(oacc[dt][2] * inv), (_Float16)(oacc[dt][3] * inv) };
        *(uint2*)(Orow + dt * 16 + g * 4) = *(const uint2*)o4;
    }
}

extern "C" void kernel_launch(void* const* d_in, const int* in_sizes, int n_in,
                              void* d_out, int out_size, void* d_ws, size_t ws_size,
                              hipStream_t stream) {
    const float* q    = (const float*)d_in[0];
    const float* k    = (const float*)d_in[1];
    const float* v    = (const float*)d_in[2];
    const float* mask = (const float*)d_in[3];
    const float* wq   = (const float*)d_in[4];
    const float* bq   = (const float*)d_in[5];
    const float* wk   = (const float*)d_in[6];
    const float* bk   = (const float*)d_in[7];
    const float* wv   = (const float*)d_in[8];
    const float* bv   = (const float*)d_in[9];
    const float* wo   = (const float*)d_in[10];
    const float* bo   = (const float*)d_in[11];

    // workspace (f16): Wt 2 MiB; Qws,Kws,VTws,Ows 8 MiB each = 34 MiB
    const size_t P8 = (size_t)MR * DM;
    _Float16* Wt   = (_Float16*)d_ws;
    _Float16* Qws  = Wt + (size_t)4 * DM * DM;
    _Float16* Kws  = Qws + P8;
    _Float16* VTws = Kws + P8;
    _Float16* Ows  = VTws + P8;

    cvt_w<<<dim3(8, 8, 4), 256, 0, stream>>>(wq, wk, wv, wo, Wt);

    proj_qkv<<<dim3(MR / 128, DM / 64, 3), 256, 0, stream>>>(
        q, k, v, Wt, bq, bk, bv, Qws, Kws, VTws);

    flash_mfma<<<dim3(SEQ / 64, NB * NH), 256, 0, stream>>>(Qws, Kws, VTws, mask, Ows);

    gemm_out<<<dim3(MR / 128, DM / 64), 256, 0, stream>>>(
        Ows, Wt + (size_t)3 * DM * DM, bo, (float*)d_out);
}

// Round 9
// 360.764 us; speedup vs baseline: 1.4933x; 1.4933x over previous
//
#include <hip/hip_runtime.h>

// MultiHeadAttention: B=2, S=4096, D=512, H=8, depth=64. fp32 in/out.
// mfma_f32_16x16x32_f16 everywhere, fp32 accum. S^T = K Q^T flash (one q-row
// per lane, register-shuffled P). Round 9: flash staging via async
// global_load_lds (16B) into double-buffered, XOR-chunk-swizzled LDS tiles
// (no VGPR staging -> no spills; round-8 register prefetch spilled 742 MB).
// GEMMs/launcher = round 7 (known-good). Q pre-scaled by log2(e).
#define NH   8
#define DH   64
#define NB   2
#define SEQ  4096
#define DM   512
#define MR   (NB * SEQ)
#define LSTR 72          // padded LDS row stride (halves) for GEMM kernels
#define LOG2E 1.44269504089f

using f16x8 = __attribute__((ext_vector_type(8))) _Float16;
using f32x4 = __attribute__((ext_vector_type(4))) float;
#define MFMA16(a, b, c) __builtin_amdgcn_mfma_f32_16x16x32_f16(a, b, c, 0, 0, 0)

__device__ __forceinline__ unsigned pk_f16(float a, float b) {
    typedef __fp16 fp16v2 __attribute__((ext_vector_type(2)));
    union { fp16v2 h; unsigned u; } c;
    c.h = __builtin_amdgcn_cvt_pkrtz(a, b);   // v_cvt_pkrtz_f16_f32
    return c.u;
}
__device__ __forceinline__ unsigned sel_shfl(unsigned a, unsigned b, int pick, int src) {
    const unsigned va = __shfl(a, src);
    const unsigned vb = __shfl(b, src);
    return pick ? vb : va;
}
// async 16B/lane global -> LDS (lds dest = wave-uniform base + lane*16)
__device__ __forceinline__ void async16(void* lds, const void* g) {
    __builtin_amdgcn_global_load_lds(
        (__attribute__((address_space(1))) void*)g,
        (__attribute__((address_space(3))) void*)lds, 16, 0, 0);
}

// ---------------------------------------------------------------------------
// W fp32 [k][n] -> Wt f16 [n][k], 4 weights (blockIdx.z). grid (8,8,4) x 256.
// ---------------------------------------------------------------------------
__global__ __launch_bounds__(256) void cvt_w(
    const float* __restrict__ w0, const float* __restrict__ w1,
    const float* __restrict__ w2, const float* __restrict__ w3,
    _Float16* __restrict__ Wt)
{
    __shared__ _Float16 T[64 * LSTR];
    const int z = blockIdx.z;
    const float* W = (z == 0) ? w0 : (z == 1 ? w1 : (z == 2 ? w2 : w3));
    _Float16* out = Wt + (size_t)z * DM * DM;
    const int t = threadIdx.x;
    const int k0 = blockIdx.x * 64, n0 = blockIdx.y * 64;
#pragma unroll
    for (int i = 0; i < 4; ++i) {
        const int kl  = i * 16 + (t >> 4);
        const int nl4 = (t & 15) * 4;
        float4 u = *(const float4*)(W + (size_t)(k0 + kl) * DM + n0 + nl4);
        T[(nl4 + 0) * LSTR + kl] = (_Float16)u.x;
        T[(nl4 + 1) * LSTR + kl] = (_Float16)u.y;
        T[(nl4 + 2) * LSTR + kl] = (_Float16)u.z;
        T[(nl4 + 3) * LSTR + kl] = (_Float16)u.w;
    }
    __syncthreads();
#pragma unroll
    for (int i = 0; i < 2; ++i) {
        const int nl = i * 32 + (t >> 3);
        const int kc = (t & 7) * 8;
        *(uint4*)(out + (size_t)(n0 + nl) * DM + k0 + kc) = *(const uint4*)&T[nl * LSTR + kc];
    }
}

// ---------------------------------------------------------------------------
// GEMM: C[M,512] = X[M,512] @ W(via Wt f16 [n][k]); val = scale*(acc+bias).
// XMODE 0: X fp32 global input (convert during staging); 1: X f16 workspace.
// OMODE 0: f16 head-split [B,H,S,64]; 1: f16 transposed [B,H,64,S] (V);
// OMODE 2: fp32 flat [M,512]. grid (M/128, 8), block 256.
// ---------------------------------------------------------------------------
template<int XMODE, int OMODE>
__global__ __launch_bounds__(256) void gemm_mfma(const void* __restrict__ Xv,
                                                 const _Float16* __restrict__ Wt,
                                                 const float* __restrict__ bias,
                                                 float scale,
                                                 void* __restrict__ outv)
{
    __shared__ _Float16 Xs[128 * LSTR];   // [row][k]
    __shared__ _Float16 Ws[64 * LSTR];    // [n][k]

    const int t = threadIdx.x;
    const int l = t & 63, w = t >> 6;
    const int m = l & 15, g = l >> 4;
    const int row0 = blockIdx.x * 128;
    const int col0 = blockIdx.y * 64;

    f32x4 acc[2][4] = {};

    for (int k0 = 0; k0 < DM; k0 += 64) {
        if (XMODE == 0) {
            const float* X = (const float*)Xv;
#pragma unroll
            for (int i = 0; i < 8; ++i) {
                const int r  = i * 16 + (t >> 4);
                const int c4 = (t & 15) * 4;
                float4 u = *(const float4*)(X + (size_t)(row0 + r) * DM + k0 + c4);
                uint2 p = make_uint2(pk_f16(u.x, u.y), pk_f16(u.z, u.w));
                *(uint2*)&Xs[r * LSTR + c4] = p;
            }
        } else {
            const _Float16* X = (const _Float16*)Xv;
#pragma unroll
            for (int i = 0; i < 4; ++i) {
                const int r  = i * 32 + (t >> 3);
                const int c8 = (t & 7) * 8;
                *(uint4*)&Xs[r * LSTR + c8] =
                    *(const uint4*)(X + (size_t)(row0 + r) * DM + k0 + c8);
            }
        }
#pragma unroll
        for (int i = 0; i < 2; ++i) {
            const int n  = i * 32 + (t >> 3);
            const int c8 = (t & 7) * 8;
            *(uint4*)&Ws[n * LSTR + c8] =
                *(const uint4*)(Wt + (size_t)(col0 + n) * DM + k0 + c8);
        }
        __syncthreads();

#pragma unroll
        for (int kk = 0; kk < 2; ++kk) {
            f16x8 a0 = *(const f16x8*)&Xs[(w * 32 + m) * LSTR + kk * 32 + g * 8];
            f16x8 a1 = *(const f16x8*)&Xs[(w * 32 + 16 + m) * LSTR + kk * 32 + g * 8];
#pragma unroll
            for (int ct = 0; ct < 4; ++ct) {
                f16x8 bf = *(const f16x8*)&Ws[(ct * 16 + m) * LSTR + kk * 32 + g * 8];
                acc[0][ct] = MFMA16(a0, bf, acc[0][ct]);
                acc[1][ct] = MFMA16(a1, bf, acc[1][ct]);
            }
        }
        __syncthreads();
    }

    float bv4[4];
#pragma unroll
    for (int ct = 0; ct < 4; ++ct) bv4[ct] = bias[col0 + ct * 16 + m];

    if (OMODE == 1) {
        // transpose 128x64 tile in LDS (reuse Xs as T[64][136])
        _Float16* T = Xs;
#pragma unroll
        for (int rt = 0; rt < 2; ++rt)
#pragma unroll
            for (int reg = 0; reg < 4; ++reg) {
                const int s_l = w * 32 + rt * 16 + g * 4 + reg;
#pragma unroll
                for (int ct = 0; ct < 4; ++ct) {
                    const int d = ct * 16 + m;
                    T[d * 136 + s_l] = (_Float16)(scale * (acc[rt][ct][reg] + bv4[ct]));
                }
            }
        __syncthreads();
        const int bb = row0 >> 12;
        const int s0 = row0 & (SEQ - 1);
        _Float16* out = (_Float16*)outv;   // [B,H,64,S]
#pragma unroll
        for (int j = 0; j < 4; ++j) {
            const int c = j * 256 + t;
            const int d = c >> 4;
            const int sc = (c & 15) * 8;
            *(uint4*)(out + (((size_t)bb * NH + blockIdx.y) * DH + d) * SEQ + s0 + sc) =
                *(const uint4*)&T[d * 136 + sc];
        }
    } else {
#pragma unroll
        for (int rt = 0; rt < 2; ++rt)
#pragma unroll
            for (int reg = 0; reg < 4; ++reg) {
                const int row = row0 + w * 32 + rt * 16 + g * 4 + reg;
#pragma unroll
                for (int ct = 0; ct < 4; ++ct) {
                    const float val = scale * (acc[rt][ct][reg] + bv4[ct]);
                    if (OMODE == 0) {
                        const int bb = row >> 12;
                        const int s  = row & (SEQ - 1);
                        ((_Float16*)outv)[(((size_t)bb * NH + blockIdx.y) * SEQ + s) * DH
                                          + ct * 16 + m] = (_Float16)val;
                    } else {
                        ((float*)outv)[(size_t)row * DM + col0 + ct * 16 + m] = val;
                    }
                }
            }
    }
}

// ---------------------------------------------------------------------------
// Flash attention, S^T formulation, async double-buffered K/V staging.
// Q(log2e-scaled),K f16 [B*H,S,64]; VT f16 [B*H,64,S]; mask fp32 [B,1,1,S];
// O f16 [B,S,512]. grid (S/64, B*H), block 256 (4 waves, wave w owns q-rows
// w*16 + (lane&15)). LDS tiles: 64 rows x 64 halves (128 B), XOR-chunk
// swizzle (slot = chunk ^ (row&7)) applied on the GLOBAL address side so
// global_load_lds's fixed lane->LDS mapping realizes it. 40 KB -> 4 blk/CU.
// One barrier per tile: sync (drains tile t, issued a compute-phase ago) ->
// issue tile t+1 -> compute tile t.
// ---------------------------------------------------------------------------
__global__ __launch_bounds__(256) void flash_mfma(
    const _Float16* __restrict__ Q, const _Float16* __restrict__ K,
    const _Float16* __restrict__ VT, const float* __restrict__ mask,
    _Float16* __restrict__ O)
{
    __shared__ _Float16 Qs [64 * 64];
    __shared__ _Float16 Ks [2][64 * 64];
    __shared__ _Float16 VTs[2][64 * 64];

    const int t = threadIdx.x;
    const int l = t & 63, w = t >> 6;
    const int m = l & 15, g = l >> 4;
    const int bh = blockIdx.y;
    const int b  = bh >> 3;
    const int h  = bh & 7;
    const int q0 = blockIdx.x * 64;

    const _Float16* Qh  = Q  + (size_t)bh * SEQ * DH;
    const _Float16* Kh  = K  + (size_t)bh * SEQ * DH;
    const _Float16* VTh = VT + (size_t)bh * DH * SEQ;
    const float* maskb = mask + (size_t)b * SEQ;

    // staging geometry: wave w covers chunks c = w*128 + l and +64 (16B each)
    const int c0 = w * 128 + l, c1 = c0 + 64;
    const int r0 = c0 >> 3,     r1 = c1 >> 3;
    const int cl0 = (c0 & 7) ^ (r0 & 7), cl1 = (c1 & 7) ^ (r1 & 7);
    const int    gK0 = r0 * DH + cl0 * 8, gK1 = r1 * DH + cl1 * 8;
    const size_t gV0 = (size_t)r0 * SEQ + cl0 * 8, gV1 = (size_t)r1 * SEQ + cl1 * 8;
    const int ldsA = w * 1024, ldsB = ldsA + 512;   // halves

    // prologue: Q tile + K/V tile 0 in flight
    async16(&Qs[ldsA], Qh + (size_t)q0 * DH + gK0);
    async16(&Qs[ldsB], Qh + (size_t)q0 * DH + gK1);
    async16(&Ks[0][ldsA], Kh + gK0);
    async16(&Ks[0][ldsB], Kh + gK1);
    async16(&VTs[0][ldsA], VTh + gV0);
    async16(&VTs[0][ldsB], VTh + gV1);

    float m_r = -INFINITY, l_r = 0.f;
    f32x4 oacc[4] = {};

    // register-shuffle sources for the P^T -> B-fragment transform
    const int srcA = m + (((g * 2) & 3) << 4);
    const int srcB = m + (((g * 2 + 1) & 3) << 4);
    const int pick = g >> 1;

    const int ms = m & 7;   // row&7 for all fragment rows this lane touches

    for (int t0 = 0; t0 < SEQ; t0 += 64) {
        const int p = (t0 >> 6) & 1;
        __syncthreads();   // waits vmcnt(0): tile t0 (and Q on iter 0) landed

        if (t0 + 64 < SEQ) {
            const int tn = t0 + 64;
            async16(&Ks[p ^ 1][ldsA], Kh + (size_t)tn * DH + gK0);
            async16(&Ks[p ^ 1][ldsB], Kh + (size_t)tn * DH + gK1);
            async16(&VTs[p ^ 1][ldsA], VTh + tn + gV0);
            async16(&VTs[p ^ 1][ldsB], VTh + tn + gV1);
        }

        // ---- S^T = K Q^T : sacc[kt] rows = keys kt*16+g*4+reg, col q = m ----
        f32x4 sacc[4] = {};
#pragma unroll
        for (int kk = 0; kk < 2; ++kk) {
            const int slot = ((kk * 4 + g) ^ ms) * 8;
            f16x8 qf = *(const f16x8*)&Qs[(w * 16 + m) * 64 + slot];
#pragma unroll
            for (int kt = 0; kt < 4; ++kt) {
                f16x8 kf = *(const f16x8*)&Ks[p][(kt * 16 + m) * 64 + slot];
                sacc[kt] = MFMA16(kf, qf, sacc[kt]);
            }
        }

        // ---- mask (per-key, fma) ----
        const float mc = -1e9f * LOG2E;
#pragma unroll
        for (int kt = 0; kt < 4; ++kt) {
            const float4 mk = *(const float4*)&maskb[t0 + kt * 16 + g * 4];
            sacc[kt][0] = fmaf(mk.x, mc, sacc[kt][0]);
            sacc[kt][1] = fmaf(mk.y, mc, sacc[kt][1]);
            sacc[kt][2] = fmaf(mk.z, mc, sacc[kt][2]);
            sacc[kt][3] = fmaf(mk.w, mc, sacc[kt][3]);
        }

        // ---- online softmax, scalar state per lane (one q-row each) ----
        float rmax = -INFINITY;
#pragma unroll
        for (int kt = 0; kt < 4; ++kt) {
            rmax = fmaxf(rmax, fmaxf(fmaxf(sacc[kt][0], sacc[kt][1]),
                                     fmaxf(sacc[kt][2], sacc[kt][3])));
        }
        rmax = fmaxf(rmax, __shfl_xor(rmax, 16));
        rmax = fmaxf(rmax, __shfl_xor(rmax, 32));
        const float mnew  = fmaxf(m_r, rmax);
        const float alpha = exp2f(m_r - mnew);   // first tile: exp2(-inf)=0
        m_r = mnew;

        float psum = 0.f;
        unsigned pkw[4][2];
#pragma unroll
        for (int kt = 0; kt < 4; ++kt) {
            const float p0 = exp2f(sacc[kt][0] - mnew);
            const float p1 = exp2f(sacc[kt][1] - mnew);
            const float p2 = exp2f(sacc[kt][2] - mnew);
            const float p3 = exp2f(sacc[kt][3] - mnew);
            psum += (p0 + p1) + (p2 + p3);
            pkw[kt][0] = pk_f16(p0, p1);
            pkw[kt][1] = pk_f16(p2, p3);
        }
        l_r = l_r * alpha + psum;
#pragma unroll
        for (int dt = 0; dt < 4; ++dt)
#pragma unroll
            for (int r = 0; r < 4; ++r) oacc[dt][r] *= alpha;

        // ---- O^T += V^T P^T ; B-frag assembled by register shuffle ----
#pragma unroll
        for (int kk = 0; kk < 2; ++kk) {
            union { unsigned u[4]; f16x8 h; } pf;
            pf.u[0] = sel_shfl(pkw[2 * kk][0], pkw[2 * kk + 1][0], pick, srcA);
            pf.u[1] = sel_shfl(pkw[2 * kk][1], pkw[2 * kk + 1][1], pick, srcA);
            pf.u[2] = sel_shfl(pkw[2 * kk][0], pkw[2 * kk + 1][0], pick, srcB);
            pf.u[3] = sel_shfl(pkw[2 * kk][1], pkw[2 * kk + 1][1], pick, srcB);
            const int slot = ((kk * 4 + g) ^ ms) * 8;
#pragma unroll
            for (int dt = 0; dt < 4; ++dt) {
                f16x8 vf = *(const f16x8*)&VTs[p][(dt * 16 + m) * 64 + slot];
                oacc[dt] = MFMA16(vf, pf.h, oacc[dt]);
            }
        }
        // next iteration's barrier guards buffer reuse
    }

    // ---- final l reduction + store (O^T: lane q = m, dims dt*16+g*4+reg) ----
    l_r += __shfl_xor(l_r, 16);
    l_r += __shfl_xor(l_r, 32);
    const float inv = 1.0f / l_r;
    const int q = q0 + w * 16 + m;
    _Float16* Orow = O + ((size_t)b * SEQ + q) * DM + h * DH;
#pragma unroll
    for (int dt = 0; dt < 4; ++dt) {
        _Float16 o4[4] = { (_Float16)(oacc[dt][0] * inv), (_Float16)(oacc[dt][1] * inv),
                           (_Float16)(oacc[dt][2] * inv), (_Float16)(oacc[dt][3] * inv) };
        *(uint2*)(Orow + dt * 16 + g * 4) = *(const uint2*)o4;
    }
}

extern "C" void kernel_launch(void* const* d_in, const int* in_sizes, int n_in,
                              void* d_out, int out_size, void* d_ws, size_t ws_size,
                              hipStream_t stream) {
    const float* q    = (const float*)d_in[0];
    const float* k    = (const float*)d_in[1];
    const float* v    = (const float*)d_in[2];
    const float* mask = (const float*)d_in[3];
    const float* wq   = (const float*)d_in[4];
    const float* bq   = (const float*)d_in[5];
    const float* wk   = (const float*)d_in[6];
    const float* bk   = (const float*)d_in[7];
    const float* wv   = (const float*)d_in[8];
    const float* bv   = (const float*)d_in[9];
    const float* wo   = (const float*)d_in[10];
    const float* bo   = (const float*)d_in[11];

    // workspace (f16): Wt 2 MiB; Qws,Kws,VTws,Ows 8 MiB each = 34 MiB
    const size_t P8 = (size_t)MR * DM;
    _Float16* Wt   = (_Float16*)d_ws;
    _Float16* Qws  = Wt + (size_t)4 * DM * DM;
    _Float16* Kws  = Qws + P8;
    _Float16* VTws = Kws + P8;
    _Float16* Ows  = VTws + P8;

    cvt_w<<<dim3(8, 8, 4), 256, 0, stream>>>(wq, wk, wv, wo, Wt);

    const dim3 gg(MR / 128, DM / 64);   // 64 x 8
    gemm_mfma<0, 0><<<gg, 256, 0, stream>>>(q, Wt,               bq, LOG2E, Qws);
    gemm_mfma<0, 0><<<gg, 256, 0, stream>>>(k, Wt + DM * DM,     bk, 1.0f,  Kws);
    gemm_mfma<0, 1><<<gg, 256, 0, stream>>>(v, Wt + 2 * DM * DM, bv, 1.0f,  VTws);

    flash_mfma<<<dim3(SEQ / 64, NB * NH), 256, 0, stream>>>(Qws, Kws, VTws, mask, Ows);

    gemm_mfma<1, 2><<<gg, 256, 0, stream>>>(Ows, Wt + 3 * DM * DM, bo, 1.0f, d_out);
}

// Round 10
// 360.172 us; speedup vs baseline: 1.4958x; 1.0016x over previous
//
#include <hip/hip_runtime.h>

// MultiHeadAttention: B=2, S=4096, D=512, H=8, depth=64. fp32 in/out.
// mfma_f32_16x16x32_f16 everywhere, fp32 accum. S^T = K Q^T flash (one q-row
// per lane, register-shuffled P). Round 10: Q fragments live in registers
// (no Qs LDS -> 32 KB LDS = 5 blocks/CU), conditional alpha-rescale
// (ballot-uniform skip when running max unchanged). K/V staging stays async
// global_load_lds, double-buffered, XOR-chunk swizzled (round 9).
#define NH   8
#define DH   64
#define NB   2
#define SEQ  4096
#define DM   512
#define MR   (NB * SEQ)
#define LSTR 72          // padded LDS row stride (halves) for GEMM kernels
#define LOG2E 1.44269504089f

using f16x8 = __attribute__((ext_vector_type(8))) _Float16;
using f32x4 = __attribute__((ext_vector_type(4))) float;
#define MFMA16(a, b, c) __builtin_amdgcn_mfma_f32_16x16x32_f16(a, b, c, 0, 0, 0)

__device__ __forceinline__ unsigned pk_f16(float a, float b) {
    typedef __fp16 fp16v2 __attribute__((ext_vector_type(2)));
    union { fp16v2 h; unsigned u; } c;
    c.h = __builtin_amdgcn_cvt_pkrtz(a, b);   // v_cvt_pkrtz_f16_f32
    return c.u;
}
__device__ __forceinline__ unsigned sel_shfl(unsigned a, unsigned b, int pick, int src) {
    const unsigned va = __shfl(a, src);
    const unsigned vb = __shfl(b, src);
    return pick ? vb : va;
}
// async 16B/lane global -> LDS (lds dest = wave-uniform base + lane*16)
__device__ __forceinline__ void async16(void* lds, const void* g) {
    __builtin_amdgcn_global_load_lds(
        (__attribute__((address_space(1))) void*)g,
        (__attribute__((address_space(3))) void*)lds, 16, 0, 0);
}

// ---------------------------------------------------------------------------
// W fp32 [k][n] -> Wt f16 [n][k], 4 weights (blockIdx.z). grid (8,8,4) x 256.
// ---------------------------------------------------------------------------
__global__ __launch_bounds__(256) void cvt_w(
    const float* __restrict__ w0, const float* __restrict__ w1,
    const float* __restrict__ w2, const float* __restrict__ w3,
    _Float16* __restrict__ Wt)
{
    __shared__ _Float16 T[64 * LSTR];
    const int z = blockIdx.z;
    const float* W = (z == 0) ? w0 : (z == 1 ? w1 : (z == 2 ? w2 : w3));
    _Float16* out = Wt + (size_t)z * DM * DM;
    const int t = threadIdx.x;
    const int k0 = blockIdx.x * 64, n0 = blockIdx.y * 64;
#pragma unroll
    for (int i = 0; i < 4; ++i) {
        const int kl  = i * 16 + (t >> 4);
        const int nl4 = (t & 15) * 4;
        float4 u = *(const float4*)(W + (size_t)(k0 + kl) * DM + n0 + nl4);
        T[(nl4 + 0) * LSTR + kl] = (_Float16)u.x;
        T[(nl4 + 1) * LSTR + kl] = (_Float16)u.y;
        T[(nl4 + 2) * LSTR + kl] = (_Float16)u.z;
        T[(nl4 + 3) * LSTR + kl] = (_Float16)u.w;
    }
    __syncthreads();
#pragma unroll
    for (int i = 0; i < 2; ++i) {
        const int nl = i * 32 + (t >> 3);
        const int kc = (t & 7) * 8;
        *(uint4*)(out + (size_t)(n0 + nl) * DM + k0 + kc) = *(const uint4*)&T[nl * LSTR + kc];
    }
}

// ---------------------------------------------------------------------------
// GEMM: C[M,512] = X[M,512] @ W(via Wt f16 [n][k]); val = scale*(acc+bias).
// XMODE 0: X fp32 global input (convert during staging); 1: X f16 workspace.
// OMODE 0: f16 head-split [B,H,S,64]; 1: f16 transposed [B,H,64,S] (V);
// OMODE 2: fp32 flat [M,512]. grid (M/128, 8), block 256.
// ---------------------------------------------------------------------------
template<int XMODE, int OMODE>
__global__ __launch_bounds__(256) void gemm_mfma(const void* __restrict__ Xv,
                                                 const _Float16* __restrict__ Wt,
                                                 const float* __restrict__ bias,
                                                 float scale,
                                                 void* __restrict__ outv)
{
    __shared__ _Float16 Xs[128 * LSTR];   // [row][k]
    __shared__ _Float16 Ws[64 * LSTR];    // [n][k]

    const int t = threadIdx.x;
    const int l = t & 63, w = t >> 6;
    const int m = l & 15, g = l >> 4;
    const int row0 = blockIdx.x * 128;
    const int col0 = blockIdx.y * 64;

    f32x4 acc[2][4] = {};

    for (int k0 = 0; k0 < DM; k0 += 64) {
        if (XMODE == 0) {
            const float* X = (const float*)Xv;
#pragma unroll
            for (int i = 0; i < 8; ++i) {
                const int r  = i * 16 + (t >> 4);
                const int c4 = (t & 15) * 4;
                float4 u = *(const float4*)(X + (size_t)(row0 + r) * DM + k0 + c4);
                uint2 p = make_uint2(pk_f16(u.x, u.y), pk_f16(u.z, u.w));
                *(uint2*)&Xs[r * LSTR + c4] = p;
            }
        } else {
            const _Float16* X = (const _Float16*)Xv;
#pragma unroll
            for (int i = 0; i < 4; ++i) {
                const int r  = i * 32 + (t >> 3);
                const int c8 = (t & 7) * 8;
                *(uint4*)&Xs[r * LSTR + c8] =
                    *(const uint4*)(X + (size_t)(row0 + r) * DM + k0 + c8);
            }
        }
#pragma unroll
        for (int i = 0; i < 2; ++i) {
            const int n  = i * 32 + (t >> 3);
            const int c8 = (t & 7) * 8;
            *(uint4*)&Ws[n * LSTR + c8] =
                *(const uint4*)(Wt + (size_t)(col0 + n) * DM + k0 + c8);
        }
        __syncthreads();

#pragma unroll
        for (int kk = 0; kk < 2; ++kk) {
            f16x8 a0 = *(const f16x8*)&Xs[(w * 32 + m) * LSTR + kk * 32 + g * 8];
            f16x8 a1 = *(const f16x8*)&Xs[(w * 32 + 16 + m) * LSTR + kk * 32 + g * 8];
#pragma unroll
            for (int ct = 0; ct < 4; ++ct) {
                f16x8 bf = *(const f16x8*)&Ws[(ct * 16 + m) * LSTR + kk * 32 + g * 8];
                acc[0][ct] = MFMA16(a0, bf, acc[0][ct]);
                acc[1][ct] = MFMA16(a1, bf, acc[1][ct]);
            }
        }
        __syncthreads();
    }

    float bv4[4];
#pragma unroll
    for (int ct = 0; ct < 4; ++ct) bv4[ct] = bias[col0 + ct * 16 + m];

    if (OMODE == 1) {
        // transpose 128x64 tile in LDS (reuse Xs as T[64][136])
        _Float16* T = Xs;
#pragma unroll
        for (int rt = 0; rt < 2; ++rt)
#pragma unroll
            for (int reg = 0; reg < 4; ++reg) {
                const int s_l = w * 32 + rt * 16 + g * 4 + reg;
#pragma unroll
                for (int ct = 0; ct < 4; ++ct) {
                    const int d = ct * 16 + m;
                    T[d * 136 + s_l] = (_Float16)(scale * (acc[rt][ct][reg] + bv4[ct]));
                }
            }
        __syncthreads();
        const int bb = row0 >> 12;
        const int s0 = row0 & (SEQ - 1);
        _Float16* out = (_Float16*)outv;   // [B,H,64,S]
#pragma unroll
        for (int j = 0; j < 4; ++j) {
            const int c = j * 256 + t;
            const int d = c >> 4;
            const int sc = (c & 15) * 8;
            *(uint4*)(out + (((size_t)bb * NH + blockIdx.y) * DH + d) * SEQ + s0 + sc) =
                *(const uint4*)&T[d * 136 + sc];
        }
    } else {
#pragma unroll
        for (int rt = 0; rt < 2; ++rt)
#pragma unroll
            for (int reg = 0; reg < 4; ++reg) {
                const int row = row0 + w * 32 + rt * 16 + g * 4 + reg;
#pragma unroll
                for (int ct = 0; ct < 4; ++ct) {
                    const float val = scale * (acc[rt][ct][reg] + bv4[ct]);
                    if (OMODE == 0) {
                        const int bb = row >> 12;
                        const int s  = row & (SEQ - 1);
                        ((_Float16*)outv)[(((size_t)bb * NH + blockIdx.y) * SEQ + s) * DH
                                          + ct * 16 + m] = (_Float16)val;
                    } else {
                        ((float*)outv)[(size_t)row * DM + col0 + ct * 16 + m] = val;
                    }
                }
            }
    }
}

// ---------------------------------------------------------------------------
// Flash attention, S^T formulation, async double-buffered K/V staging.
// Q(log2e-scaled),K f16 [B*H,S,64]; VT f16 [B*H,64,S]; mask fp32 [B,1,1,S];
// O f16 [B,S,512]. grid (S/64, B*H), block 256 (4 waves, wave w owns q-rows
// w*16 + (lane&15)). Q fragments in registers (loaded once). LDS: K/V
// double-buffered 64x64-half tiles, XOR-chunk swizzle on the GLOBAL address
// side. 32 KB -> 5 blocks/CU. One barrier per tile.
// ---------------------------------------------------------------------------
__global__ __launch_bounds__(256) void flash_mfma(
    const _Float16* __restrict__ Q, const _Float16* __restrict__ K,
    const _Float16* __restrict__ VT, const float* __restrict__ mask,
    _Float16* __restrict__ O)
{
    __shared__ _Float16 Ks [2][64 * 64];
    __shared__ _Float16 VTs[2][64 * 64];

    const int t = threadIdx.x;
    const int l = t & 63, w = t >> 6;
    const int m = l & 15, g = l >> 4;
    const int bh = blockIdx.y;
    const int b  = bh >> 3;
    const int h  = bh & 7;
    const int q0 = blockIdx.x * 64;

    const _Float16* Qh  = Q  + (size_t)bh * SEQ * DH;
    const _Float16* Kh  = K  + (size_t)bh * SEQ * DH;
    const _Float16* VTh = VT + (size_t)bh * DH * SEQ;
    const float* maskb = mask + (size_t)b * SEQ;

    // staging geometry: wave w covers chunks c = w*128 + l and +64 (16B each)
    const int c0 = w * 128 + l, c1 = c0 + 64;
    const int r0 = c0 >> 3,     r1 = c1 >> 3;
    const int cl0 = (c0 & 7) ^ (r0 & 7), cl1 = (c1 & 7) ^ (r1 & 7);
    const int    gK0 = r0 * DH + cl0 * 8, gK1 = r1 * DH + cl1 * 8;
    const size_t gV0 = (size_t)r0 * SEQ + cl0 * 8, gV1 = (size_t)r1 * SEQ + cl1 * 8;
    const int ldsA = w * 1024, ldsB = ldsA + 512;   // halves

    // prologue: K/V tile 0 in flight
    async16(&Ks[0][ldsA], Kh + gK0);
    async16(&Ks[0][ldsB], Kh + gK1);
    async16(&VTs[0][ldsA], VTh + gV0);
    async16(&VTs[0][ldsB], VTh + gV1);

    // Q fragments in registers (wave w only ever needs q-rows w*16+m)
    f16x8 qf[2];
#pragma unroll
    for (int kk = 0; kk < 2; ++kk)
        qf[kk] = *(const f16x8*)(Qh + (size_t)(q0 + w * 16 + m) * DH + kk * 32 + g * 8);

    float m_r = -INFINITY, l_r = 0.f;
    f32x4 oacc[4] = {};

    // register-shuffle sources for the P^T -> B-fragment transform
    const int srcA = m + (((g * 2) & 3) << 4);
    const int srcB = m + (((g * 2 + 1) & 3) << 4);
    const int pick = g >> 1;

    const int ms = m & 7;   // row&7 for all fragment rows this lane touches

    for (int t0 = 0; t0 < SEQ; t0 += 64) {
        const int p = (t0 >> 6) & 1;
        __syncthreads();   // waits vmcnt(0): tile t0 landed

        if (t0 + 64 < SEQ) {
            const int tn = t0 + 64;
            async16(&Ks[p ^ 1][ldsA], Kh + (size_t)tn * DH + gK0);
            async16(&Ks[p ^ 1][ldsB], Kh + (size_t)tn * DH + gK1);
            async16(&VTs[p ^ 1][ldsA], VTh + tn + gV0);
            async16(&VTs[p ^ 1][ldsB], VTh + tn + gV1);
        }

        // ---- S^T = K Q^T : sacc[kt] rows = keys kt*16+g*4+reg, col q = m ----
        f32x4 sacc[4] = {};
#pragma unroll
        for (int kk = 0; kk < 2; ++kk) {
            const int slot = ((kk * 4 + g) ^ ms) * 8;
#pragma unroll
            for (int kt = 0; kt < 4; ++kt) {
                f16x8 kf = *(const f16x8*)&Ks[p][(kt * 16 + m) * 64 + slot];
                sacc[kt] = MFMA16(kf, qf[kk], sacc[kt]);
            }
        }

        // ---- mask (per-key, fma) ----
        const float mc = -1e9f * LOG2E;
#pragma unroll
        for (int kt = 0; kt < 4; ++kt) {
            const float4 mk = *(const float4*)&maskb[t0 + kt * 16 + g * 4];
            sacc[kt][0] = fmaf(mk.x, mc, sacc[kt][0]);
            sacc[kt][1] = fmaf(mk.y, mc, sacc[kt][1]);
            sacc[kt][2] = fmaf(mk.z, mc, sacc[kt][2]);
            sacc[kt][3] = fmaf(mk.w, mc, sacc[kt][3]);
        }

        // ---- online softmax, scalar state per lane (one q-row each) ----
        float rmax = -INFINITY;
#pragma unroll
        for (int kt = 0; kt < 4; ++kt) {
            rmax = fmaxf(rmax, fmaxf(fmaxf(sacc[kt][0], sacc[kt][1]),
                                     fmaxf(sacc[kt][2], sacc[kt][3])));
        }
        rmax = fmaxf(rmax, __shfl_xor(rmax, 16));
        rmax = fmaxf(rmax, __shfl_xor(rmax, 32));
        const float mnew = fmaxf(m_r, rmax);

        float psum = 0.f;
        unsigned pkw[4][2];
#pragma unroll
        for (int kt = 0; kt < 4; ++kt) {
            const float p0 = exp2f(sacc[kt][0] - mnew);
            const float p1 = exp2f(sacc[kt][1] - mnew);
            const float p2 = exp2f(sacc[kt][2] - mnew);
            const float p3 = exp2f(sacc[kt][3] - mnew);
            psum += (p0 + p1) + (p2 + p3);
            pkw[kt][0] = pk_f16(p0, p1);
            pkw[kt][1] = pk_f16(p2, p3);
        }

        // wave-uniform skip of the rescale when no lane's max moved
        if (__ballot(mnew > m_r)) {
            const float alpha = exp2f(m_r - mnew);  // 1.0 for unchanged lanes
            l_r = l_r * alpha + psum;
#pragma unroll
            for (int dt = 0; dt < 4; ++dt)
#pragma unroll
                for (int r = 0; r < 4; ++r) oacc[dt][r] *= alpha;
        } else {
            l_r += psum;
        }
        m_r = mnew;

        // ---- O^T += V^T P^T ; B-frag assembled by register shuffle ----
#pragma unroll
        for (int kk = 0; kk < 2; ++kk) {
            union { unsigned u[4]; f16x8 h; } pf;
            pf.u[0] = sel_shfl(pkw[2 * kk][0], pkw[2 * kk + 1][0], pick, srcA);
            pf.u[1] = sel_shfl(pkw[2 * kk][1], pkw[2 * kk + 1][1], pick, srcA);
            pf.u[2] = sel_shfl(pkw[2 * kk][0], pkw[2 * kk + 1][0], pick, srcB);
            pf.u[3] = sel_shfl(pkw[2 * kk][1], pkw[2 * kk + 1][1], pick, srcB);
            const int slot = ((kk * 4 + g) ^ ms) * 8;
#pragma unroll
            for (int dt = 0; dt < 4; ++dt) {
                f16x8 vf = *(const f16x8*)&VTs[p][(dt * 16 + m) * 64 + slot];
                oacc[dt] = MFMA16(vf, pf.h, oacc[dt]);
            }
        }
        // next iteration's barrier guards buffer reuse
    }

    // ---- final l reduction + store (O^T: lane q = m, dims dt*16+g*4+reg) ----
    l_r += __shfl_xor(l_r, 16);
    l_r += __shfl_xor(l_r, 32);
    const float inv = 1.0f / l_r;
    const int q = q0 + w * 16 + m;
    _Float16* Orow = O + ((size_t)b * SEQ + q) * DM + h * DH;
#pragma unroll
    for (int dt = 0; dt < 4; ++dt) {
        _Float16 o4[4] = { (_Float16)(oacc[dt][0] * inv), (_Float16)(oacc[dt][1] * inv),
                           (_Float16)(oacc[dt][2] * inv), (_Float16)(oacc[dt][3] * inv) };
        *(uint2*)(Orow + dt * 16 + g * 4) = *(const uint2*)o4;
    }
}

extern "C" void kernel_launch(void* const* d_in, const int* in_sizes, int n_in,
                              void* d_out, int out_size, void* d_ws, size_t ws_size,
                              hipStream_t stream) {
    const float* q    = (const float*)d_in[0];
    const float* k    = (const float*)d_in[1];
    const float* v    = (const float*)d_in[2];
    const float* mask = (const float*)d_in[3];
    const float* wq   = (const float*)d_in[4];
    const float* bq   = (const float*)d_in[5];
    const float* wk   = (const float*)d_in[6];
    const float* bk   = (const float*)d_in[7];
    const float* wv   = (const float*)d_in[8];
    const float* bv   = (const float*)d_in[9];
    const float* wo   = (const float*)d_in[10];
    const float* bo   = (const float*)d_in[11];

    // workspace (f16): Wt 2 MiB; Qws,Kws,VTws,Ows 8 MiB each = 34 MiB
    const size_t P8 = (size_t)MR * DM;
    _Float16* Wt   = (_Float16*)d_ws;
    _Float16* Qws  = Wt + (size_t)4 * DM * DM;
    _Float16* Kws  = Qws + P8;
    _Float16* VTws = Kws + P8;
    _Float16* Ows  = VTws + P8;

    cvt_w<<<dim3(8, 8, 4), 256, 0, stream>>>(wq, wk, wv, wo, Wt);

    const dim3 gg(MR / 128, DM / 64);   // 64 x 8
    gemm_mfma<0, 0><<<gg, 256, 0, stream>>>(q, Wt,               bq, LOG2E, Qws);
    gemm_mfma<0, 0><<<gg, 256, 0, stream>>>(k, Wt + DM * DM,     bk, 1.0f,  Kws);
    gemm_mfma<0, 1><<<gg, 256, 0, stream>>>(v, Wt + 2 * DM * DM, bv, 1.0f,  VTws);

    flash_mfma<<<dim3(SEQ / 64, NB * NH), 256, 0, stream>>>(Qws, Kws, VTws, mask, Ows);

    gemm_mfma<1, 2><<<gg, 256, 0, stream>>>(Ows, Wt + 3 * DM * DM, bo, 1.0f, d_out);
}

// Round 11
// 296.256 us; speedup vs baseline: 1.8185x; 1.2157x over previous
//
#include <hip/hip_runtime.h>

// MultiHeadAttention: B=2, S=4096, D=512, H=8, depth=64. fp32 in/out.
// mfma_f32_16x16x32_f16 everywhere, fp32 accum. S^T = K Q^T flash (one q-row
// per lane, register-shuffled P), async double-buffered global_load_lds
// staging in ALL matmul kernels. Round 11: raw v_exp_f32 (exp2f was lowering
// to the precise OCML path without -ffast-math), mask folded into the MFMA
// C-operand init, fused async projection GEMMs.
#define NH   8
#define DH   64
#define NB   2
#define SEQ  4096
#define DM   512
#define MR   (NB * SEQ)
#define LSTR 72
#define LOG2E 1.44269504089f

using f16x8 = __attribute__((ext_vector_type(8))) _Float16;
using f32x4 = __attribute__((ext_vector_type(4))) float;
#define MFMA16(a, b, c) __builtin_amdgcn_mfma_f32_16x16x32_f16(a, b, c, 0, 0, 0)

#if defined(__has_builtin) && __has_builtin(__builtin_amdgcn_exp2f)
#define EXP2(x) __builtin_amdgcn_exp2f(x)
#else
extern "C" __device__ float __ocml_native_exp2_f32(float);
#define EXP2(x) __ocml_native_exp2_f32(x)
#endif

__device__ __forceinline__ unsigned pk_f16(float a, float b) {
    typedef __fp16 fp16v2 __attribute__((ext_vector_type(2)));
    union { fp16v2 h; unsigned u; } c;
    c.h = __builtin_amdgcn_cvt_pkrtz(a, b);
    return c.u;
}
__device__ __forceinline__ unsigned sel_shfl(unsigned a, unsigned b, int pick, int src) {
    const unsigned va = __shfl(a, src);
    const unsigned vb = __shfl(b, src);
    return pick ? vb : va;
}
// async 16B/lane global -> LDS (lds dest = wave-uniform base + lane*16)
__device__ __forceinline__ void async16(void* lds, const void* g) {
    __builtin_amdgcn_global_load_lds(
        (__attribute__((address_space(1))) void*)g,
        (__attribute__((address_space(3))) void*)lds, 16, 0, 0);
}

// ---------------------------------------------------------------------------
// W fp32 [k][n] -> Wt f16 [n][k], 4 weights. grid (8,8,4) x 256.
// ---------------------------------------------------------------------------
__global__ __launch_bounds__(256) void cvt_w(
    const float* __restrict__ w0, const float* __restrict__ w1,
    const float* __restrict__ w2, const float* __restrict__ w3,
    _Float16* __restrict__ Wt)
{
    __shared__ _Float16 T[64 * LSTR];
    const int z = blockIdx.z;
    const float* W = (z == 0) ? w0 : (z == 1 ? w1 : (z == 2 ? w2 : w3));
    _Float16* out = Wt + (size_t)z * DM * DM;
    const int t = threadIdx.x;
    const int k0 = blockIdx.x * 64, n0 = blockIdx.y * 64;
#pragma unroll
    for (int i = 0; i < 4; ++i) {
        const int kl  = i * 16 + (t >> 4);
        const int nl4 = (t & 15) * 4;
        float4 u = *(const float4*)(W + (size_t)(k0 + kl) * DM + n0 + nl4);
        T[(nl4 + 0) * LSTR + kl] = (_Float16)u.x;
        T[(nl4 + 1) * LSTR + kl] = (_Float16)u.y;
        T[(nl4 + 2) * LSTR + kl] = (_Float16)u.z;
        T[(nl4 + 3) * LSTR + kl] = (_Float16)u.w;
    }
    __syncthreads();
#pragma unroll
    for (int i = 0; i < 2; ++i) {
        const int nl = i * 32 + (t >> 3);
        const int kc = (t & 7) * 8;
        *(uint4*)(out + (size_t)(n0 + nl) * DM + k0 + kc) = *(const uint4*)&T[nl * LSTR + kc];
    }
}

// mask [B,1,1,S] fp32 -> mw = mask * (-1e9*log2e). grid 32 x 256.
__global__ __launch_bounds__(256) void maskprep(const float* __restrict__ mask,
                                                float* __restrict__ mw)
{
    const int i = blockIdx.x * 256 + threadIdx.x;
    mw[i] = mask[i] * (-1e9f * LOG2E);
}

// q,k,v fp32 -> f16 flat [MR][DM]. grid 6144 x 256, 8 elems/thread.
__global__ __launch_bounds__(256) void cvt_qkv(
    const float* __restrict__ q, const float* __restrict__ k,
    const float* __restrict__ v,
    _Float16* __restrict__ Qo, _Float16* __restrict__ Ko, _Float16* __restrict__ Vo)
{
    const size_t PER = (size_t)MR * DM;
    size_t base = ((size_t)blockIdx.x * 256 + threadIdx.x) * 8;
    const int tz = (int)(base / PER);
    const size_t off = base % PER;
    const float* s = (tz == 0) ? q : (tz == 1 ? k : v);
    _Float16* d    = (tz == 0) ? Qo : (tz == 1 ? Ko : Vo);
    float4 a = *(const float4*)(s + off);
    float4 b = *(const float4*)(s + off + 4);
    uint4 p = make_uint4(pk_f16(a.x, a.y), pk_f16(a.z, a.w),
                         pk_f16(b.x, b.y), pk_f16(b.z, b.w));
    *(uint4*)(d + off) = p;
}

// ---------------------------------------------------------------------------
// Fused QKV projection, async double-buffered. X f16 [M][512] by z;
// Wt f16 [3][n][k]. z<2: head-split f16 [B,H,S,64] (Q scaled by log2e);
// z==2: transposed [B,H,64,S]. grid (MR/128, 8, 3), block 256.
// LDS swizzle: chunk c -> row c>>3, slot c&7; data for column-chunk
// ((c&7)^(row&7)) stored there (swizzle applied on the global address side).
// ---------------------------------------------------------------------------
__global__ __launch_bounds__(256) void proj3(
    const _Float16* __restrict__ Qin, const _Float16* __restrict__ Kin,
    const _Float16* __restrict__ Vin, const _Float16* __restrict__ Wt,
    const float* __restrict__ bq, const float* __restrict__ bk,
    const float* __restrict__ bv,
    _Float16* __restrict__ Qo, _Float16* __restrict__ Ko,
    _Float16* __restrict__ VTo)
{
    __shared__ _Float16 Xs[2][128 * 64];
    __shared__ _Float16 Ws[2][64 * 64];

    const int z = blockIdx.z;
    const _Float16* X = (z == 0) ? Qin : (z == 1 ? Kin : Vin);
    const _Float16* W = Wt + (size_t)z * DM * DM;
    const float* bias = (z == 0) ? bq : (z == 1 ? bk : bv);
    const float scale = (z == 0) ? LOG2E : 1.0f;

    const int t = threadIdx.x;
    const int l = t & 63, w = t >> 6;
    const int m = l & 15, g = l >> 4;
    const int ms = m & 7;
    const int row0 = blockIdx.x * 128;
    const int col0 = blockIdx.y * 64;

    int xr[4], xsw[4];
#pragma unroll
    for (int i = 0; i < 4; ++i) {
        const int c = w * 256 + i * 64 + l;
        xr[i]  = c >> 3;
        xsw[i] = ((c & 7) ^ (xr[i] & 7)) * 8;
    }
    int wr[2], wsw[2];
#pragma unroll
    for (int i = 0; i < 2; ++i) {
        const int c = w * 128 + i * 64 + l;
        wr[i]  = c >> 3;
        wsw[i] = ((c & 7) ^ (wr[i] & 7)) * 8;
    }

    // prologue: k0 = 0 into buffer 0
#pragma unroll
    for (int i = 0; i < 4; ++i)
        async16(&Xs[0][(w * 256 + i * 64) * 8], X + (size_t)(row0 + xr[i]) * DM + xsw[i]);
#pragma unroll
    for (int i = 0; i < 2; ++i)
        async16(&Ws[0][(w * 128 + i * 64) * 8], W + (size_t)(col0 + wr[i]) * DM + wsw[i]);

    f32x4 acc[2][4] = {};

    for (int k0 = 0; k0 < DM; k0 += 64) {
        const int p = (k0 >> 6) & 1;
        __syncthreads();   // drains tile k0 (issued a full compute-phase ago)
        if (k0 + 64 < DM) {
            const int kn = k0 + 64;
#pragma unroll
            for (int i = 0; i < 4; ++i)
                async16(&Xs[p ^ 1][(w * 256 + i * 64) * 8],
                        X + (size_t)(row0 + xr[i]) * DM + kn + xsw[i]);
#pragma unroll
            for (int i = 0; i < 2; ++i)
                async16(&Ws[p ^ 1][(w * 128 + i * 64) * 8],
                        W + (size_t)(col0 + wr[i]) * DM + kn + wsw[i]);
        }
#pragma unroll
        for (int kk = 0; kk < 2; ++kk) {
            const int slot = ((kk * 4 + g) ^ ms) * 8;
            f16x8 a0 = *(const f16x8*)&Xs[p][(w * 32 + m) * 64 + slot];
            f16x8 a1 = *(const f16x8*)&Xs[p][(w * 32 + 16 + m) * 64 + slot];
#pragma unroll
            for (int ct = 0; ct < 4; ++ct) {
                f16x8 bf = *(const f16x8*)&Ws[p][(ct * 16 + m) * 64 + slot];
                acc[0][ct] = MFMA16(a0, bf, acc[0][ct]);
                acc[1][ct] = MFMA16(a1, bf, acc[1][ct]);
            }
        }
    }

    float bv4[4];
#pragma unroll
    for (int ct = 0; ct < 4; ++ct) bv4[ct] = bias[col0 + ct * 16 + m];

    if (z == 2) {
        __syncthreads();   // all waves done reading Xs
        _Float16* T = &Xs[0][0];   // reuse as T[64][136]
#pragma unroll
        for (int rt = 0; rt < 2; ++rt)
#pragma unroll
            for (int reg = 0; reg < 4; ++reg) {
                const int s_l = w * 32 + rt * 16 + g * 4 + reg;
#pragma unroll
                for (int ct = 0; ct < 4; ++ct) {
                    const int d = ct * 16 + m;
                    T[d * 136 + s_l] = (_Float16)(acc[rt][ct][reg] + bv4[ct]);
                }
            }
        __syncthreads();
        const int bb = row0 >> 12;
        const int s0 = row0 & (SEQ - 1);
#pragma unroll
        for (int j = 0; j < 4; ++j) {
            const int c = j * 256 + t;
            const int d = c >> 4;
            const int sc = (c & 15) * 8;
            *(uint4*)(VTo + (((size_t)bb * NH + blockIdx.y) * DH + d) * SEQ + s0 + sc) =
                *(const uint4*)&T[d * 136 + sc];
        }
    } else {
        _Float16* out = (z == 0) ? Qo : Ko;
#pragma unroll
        for (int rt = 0; rt < 2; ++rt)
#pragma unroll
            for (int reg = 0; reg < 4; ++reg) {
                const int row = row0 + w * 32 + rt * 16 + g * 4 + reg;
                const int bb = row >> 12;
                const int s  = row & (SEQ - 1);
#pragma unroll
                for (int ct = 0; ct < 4; ++ct)
                    out[(((size_t)bb * NH + blockIdx.y) * SEQ + s) * DH + ct * 16 + m] =
                        (_Float16)(scale * (acc[rt][ct][reg] + bv4[ct]));
            }
    }
}

// ---------------------------------------------------------------------------
// Output GEMM: d_out[M,512] fp32 = Ows[M,512](f16) @ Wo + bo. Async dbuf.
// grid (MR/128, 8), block 256.
// ---------------------------------------------------------------------------
__global__ __launch_bounds__(256) void gemm_out(const _Float16* __restrict__ X,
                                                const _Float16* __restrict__ W,
                                                const float* __restrict__ bias,
                                                float* __restrict__ out)
{
    __shared__ _Float16 Xs[2][128 * 64];
    __shared__ _Float16 Ws[2][64 * 64];

    const int t = threadIdx.x;
    const int l = t & 63, w = t >> 6;
    const int m = l & 15, g = l >> 4;
    const int ms = m & 7;
    const int row0 = blockIdx.x * 128;
    const int col0 = blockIdx.y * 64;

    int xr[4], xsw[4];
#pragma unroll
    for (int i = 0; i < 4; ++i) {
        const int c = w * 256 + i * 64 + l;
        xr[i]  = c >> 3;
        xsw[i] = ((c & 7) ^ (xr[i] & 7)) * 8;
    }
    int wr[2], wsw[2];
#pragma unroll
    for (int i = 0; i < 2; ++i) {
        const int c = w * 128 + i * 64 + l;
        wr[i]  = c >> 3;
        wsw[i] = ((c & 7) ^ (wr[i] & 7)) * 8;
    }

#pragma unroll
    for (int i = 0; i < 4; ++i)
        async16(&Xs[0][(w * 256 + i * 64) * 8], X + (size_t)(row0 + xr[i]) * DM + xsw[i]);
#pragma unroll
    for (int i = 0; i < 2; ++i)
        async16(&Ws[0][(w * 128 + i * 64) * 8], W + (size_t)(col0 + wr[i]) * DM + wsw[i]);

    f32x4 acc[2][4] = {};

    for (int k0 = 0; k0 < DM; k0 += 64) {
        const int p = (k0 >> 6) & 1;
        __syncthreads();
        if (k0 + 64 < DM) {
            const int kn = k0 + 64;
#pragma unroll
            for (int i = 0; i < 4; ++i)
                async16(&Xs[p ^ 1][(w * 256 + i * 64) * 8],
                        X + (size_t)(row0 + xr[i]) * DM + kn + xsw[i]);
#pragma unroll
            for (int i = 0; i < 2; ++i)
                async16(&Ws[p ^ 1][(w * 128 + i * 64) * 8],
                        W + (size_t)(col0 + wr[i]) * DM + kn + wsw[i]);
        }
#pragma unroll
        for (int kk = 0; kk < 2; ++kk) {
            const int slot = ((kk * 4 + g) ^ ms) * 8;
            f16x8 a0 = *(const f16x8*)&Xs[p][(w * 32 + m) * 64 + slot];
            f16x8 a1 = *(const f16x8*)&Xs[p][(w * 32 + 16 + m) * 64 + slot];
#pragma unroll
            for (int ct = 0; ct < 4; ++ct) {
                f16x8 bf = *(const f16x8*)&Ws[p][(ct * 16 + m) * 64 + slot];
                acc[0][ct] = MFMA16(a0, bf, acc[0][ct]);
                acc[1][ct] = MFMA16(a1, bf, acc[1][ct]);
            }
        }
    }

    float bv4[4];
#pragma unroll
    for (int ct = 0; ct < 4; ++ct) bv4[ct] = bias[col0 + ct * 16 + m];

#pragma unroll
    for (int rt = 0; rt < 2; ++rt)
#pragma unroll
        for (int reg = 0; reg < 4; ++reg) {
            const int row = row0 + w * 32 + rt * 16 + g * 4 + reg;
#pragma unroll
            for (int ct = 0; ct < 4; ++ct)
                out[(size_t)row * DM + col0 + ct * 16 + m] = acc[rt][ct][reg] + bv4[ct];
        }
}

// ---------------------------------------------------------------------------
// Flash attention. Q(log2e-scaled),K f16 [B*H,S,64]; VT f16 [B*H,64,S];
// mw fp32 [B][S] (pre-scaled mask, folded into the MFMA C-init);
// O f16 [B,S,512]. grid (S/64, B*H), block 256. Raw v_exp_f32 softmax.
// ---------------------------------------------------------------------------
__global__ __launch_bounds__(256) void flash_mfma(
    const _Float16* __restrict__ Q, const _Float16* __restrict__ K,
    const _Float16* __restrict__ VT, const float* __restrict__ mw,
    _Float16* __restrict__ O)
{
    __shared__ _Float16 Ks [2][64 * 64];
    __shared__ _Float16 VTs[2][64 * 64];

    const int t = threadIdx.x;
    const int l = t & 63, w = t >> 6;
    const int m = l & 15, g = l >> 4;
    const int bh = blockIdx.y;
    const int b  = bh >> 3;
    const int h  = bh & 7;
    const int q0 = blockIdx.x * 64;

    const _Float16* Qh  = Q  + (size_t)bh * SEQ * DH;
    const _Float16* Kh  = K  + (size_t)bh * SEQ * DH;
    const _Float16* VTh = VT + (size_t)bh * DH * SEQ;
    const float* mwb = mw + (size_t)b * SEQ;

    const int c0 = w * 128 + l, c1 = c0 + 64;
    const int r0 = c0 >> 3,     r1 = c1 >> 3;
    const int cl0 = (c0 & 7) ^ (r0 & 7), cl1 = (c1 & 7) ^ (r1 & 7);
    const int    gK0 = r0 * DH + cl0 * 8, gK1 = r1 * DH + cl1 * 8;
    const size_t gV0 = (size_t)r0 * SEQ + cl0 * 8, gV1 = (size_t)r1 * SEQ + cl1 * 8;
    const int ldsA = w * 1024, ldsB = ldsA + 512;

    async16(&Ks[0][ldsA], Kh + gK0);
    async16(&Ks[0][ldsB], Kh + gK1);
    async16(&VTs[0][ldsA], VTh + gV0);
    async16(&VTs[0][ldsB], VTh + gV1);

    // Q fragments in registers (wave w only needs q-row w*16 + m)
    f16x8 qf[2];
#pragma unroll
    for (int kk = 0; kk < 2; ++kk)
        qf[kk] = *(const f16x8*)(Qh + (size_t)(q0 + w * 16 + m) * DH + kk * 32 + g * 8);

    float m_r = -INFINITY, l_r = 0.f;
    f32x4 oacc[4] = {};

    const int srcA = m + (((g * 2) & 3) << 4);
    const int srcB = m + (((g * 2 + 1) & 3) << 4);
    const int pick = g >> 1;
    const int ms = m & 7;

    for (int t0 = 0; t0 < SEQ; t0 += 64) {
        const int p = (t0 >> 6) & 1;
        __syncthreads();   // tile t0 landed

        if (t0 + 64 < SEQ) {
            const int tn = t0 + 64;
            async16(&Ks[p ^ 1][ldsA], Kh + (size_t)tn * DH + gK0);
            async16(&Ks[p ^ 1][ldsB], Kh + (size_t)tn * DH + gK1);
            async16(&VTs[p ^ 1][ldsA], VTh + tn + gV0);
            async16(&VTs[p ^ 1][ldsB], VTh + tn + gV1);
        }

        // ---- S^T = K Q^T + mask (mask pre-scaled, as MFMA C-init) ----
        f32x4 sacc[4];
#pragma unroll
        for (int kt = 0; kt < 4; ++kt)
            sacc[kt] = *(const f32x4*)&mwb[t0 + kt * 16 + g * 4];
#pragma unroll
        for (int kk = 0; kk < 2; ++kk) {
            const int slot = ((kk * 4 + g) ^ ms) * 8;
#pragma unroll
            for (int kt = 0; kt < 4; ++kt) {
                f16x8 kf = *(const f16x8*)&Ks[p][(kt * 16 + m) * 64 + slot];
                sacc[kt] = MFMA16(kf, qf[kk], sacc[kt]);
            }
        }

        // ---- online softmax, scalar state per lane (one q-row each) ----
        float rmax = -INFINITY;
#pragma unroll
        for (int kt = 0; kt < 4; ++kt)
            rmax = fmaxf(rmax, fmaxf(fmaxf(sacc[kt][0], sacc[kt][1]),
                                     fmaxf(sacc[kt][2], sacc[kt][3])));
        rmax = fmaxf(rmax, __shfl_xor(rmax, 16));
        rmax = fmaxf(rmax, __shfl_xor(rmax, 32));
        const float mnew  = fmaxf(m_r, rmax);
        const float alpha = EXP2(m_r - mnew);   // first tile: exp2(-inf)=0
        m_r = mnew;

        float psum = 0.f;
        unsigned pkw[4][2];
#pragma unroll
        for (int kt = 0; kt < 4; ++kt) {
            const float p0 = EXP2(sacc[kt][0] - mnew);
            const float p1 = EXP2(sacc[kt][1] - mnew);
            const float p2 = EXP2(sacc[kt][2] - mnew);
            const float p3 = EXP2(sacc[kt][3] - mnew);
            psum += (p0 + p1) + (p2 + p3);
            pkw[kt][0] = pk_f16(p0, p1);
            pkw[kt][1] = pk_f16(p2, p3);
        }
        l_r = l_r * alpha + psum;
#pragma unroll
        for (int dt = 0; dt < 4; ++dt)
#pragma unroll
            for (int r = 0; r < 4; ++r) oacc[dt][r] *= alpha;

        // ---- O^T += V^T P^T ; B-frag assembled by register shuffle ----
#pragma unroll
        for (int kk = 0; kk < 2; ++kk) {
            union { unsigned u[4]; f16x8 h; } pf;
            pf.u[0] = sel_shfl(pkw[2 * kk][0], pkw[2 * kk + 1][0], pick, srcA);
            pf.u[1] = sel_shfl(pkw[2 * kk][1], pkw[2 * kk + 1][1], pick, srcA);
            pf.u[2] = sel_shfl(pkw[2 * kk][0], pkw[2 * kk + 1][0], pick, srcB);
            pf.u[3] = sel_shfl(pkw[2 * kk][1], pkw[2 * kk + 1][1], pick, srcB);
            const int slot = ((kk * 4 + g) ^ ms) * 8;
#pragma unroll
            for (int dt = 0; dt < 4; ++dt) {
                f16x8 vf = *(const f16x8*)&VTs[p][(dt * 16 + m) * 64 + slot];
                oacc[dt] = MFMA16(vf, pf.h, oacc[dt]);
            }
        }
    }

    // ---- final l reduction + store ----
    l_r += __shfl_xor(l_r, 16);
    l_r += __shfl_xor(l_r, 32);
    const float inv = 1.0f / l_r;
    const int q = q0 + w * 16 + m;
    _Float16* Orow = O + ((size_t)b * SEQ + q) * DM + h * DH;
#pragma unroll
    for (int dt = 0; dt < 4; ++dt) {
        _Float16 o4[4] = { (_Float16)(oacc[dt][0] * inv), (_Float16)(oacc[dt][1] * inv),
                           (_Float16)(oacc[dt][2] * inv), (_Float16)(oacc[dt][3] * inv) };
        *(uint2*)(Orow + dt * 16 + g * 4) = *(const uint2*)o4;
    }
}

extern "C" void kernel_launch(void* const* d_in, const int* in_sizes, int n_in,
                              void* d_out, int out_size, void* d_ws, size_t ws_size,
                              hipStream_t stream) {
    const float* q    = (const float*)d_in[0];
    const float* k    = (const float*)d_in[1];
    const float* v    = (const float*)d_in[2];
    const float* mask = (const float*)d_in[3];
    const float* wq   = (const float*)d_in[4];
    const float* bq   = (const float*)d_in[5];
    const float* wk   = (const float*)d_in[6];
    const float* bk   = (const float*)d_in[7];
    const float* wv   = (const float*)d_in[8];
    const float* bv   = (const float*)d_in[9];
    const float* wo   = (const float*)d_in[10];
    const float* bo   = (const float*)d_in[11];

    // workspace (~59 MB): Wt 2MB | mw 32KB | Qin,Kin,Vin f16 | Qws,Kws,VTws,Ows f16
    const size_t P8 = (size_t)MR * DM;
    _Float16* Wt  = (_Float16*)d_ws;
    float*    mw  = (float*)(Wt + (size_t)4 * DM * DM);
    _Float16* Qin = (_Float16*)(mw + NB * SEQ);
    _Float16* Kin = Qin + P8;
    _Float16* Vin = Kin + P8;
    _Float16* Qws = Vin + P8;
    _Float16* Kws = Qws + P8;
    _Float16* VTws = Kws + P8;
    _Float16* Ows  = VTws + P8;

    cvt_w<<<dim3(8, 8, 4), 256, 0, stream>>>(wq, wk, wv, wo, Wt);
    maskprep<<<dim3(NB * SEQ / 256), 256, 0, stream>>>(mask, mw);
    cvt_qkv<<<dim3(3 * (MR * DM / 8) / 256), 256, 0, stream>>>(q, k, v, Qin, Kin, Vin);

    proj3<<<dim3(MR / 128, DM / 64, 3), 256, 0, stream>>>(
        Qin, Kin, Vin, Wt, bq, bk, bv, Qws, Kws, VTws);

    flash_mfma<<<dim3(SEQ / 64, NB * NH), 256, 0, stream>>>(Qws, Kws, VTws, mw, Ows);

    gemm_out<<<dim3(MR / 128, DM / 64), 256, 0, stream>>>(
        Ows, Wt + (size_t)3 * DM * DM, bo, (float*)d_out);
}